// Round 6
// baseline (332.437 us; speedup 1.0000x reference)
//
#include <hip/hip_runtime.h>

typedef unsigned short ushort_t;
typedef __attribute__((ext_vector_type(8))) short short8;
typedef __attribute__((ext_vector_type(4))) float f32x4;
typedef __attribute__((ext_vector_type(4))) int int4v;

#define RNUM 8
#define FDIM 128

__device__ __forceinline__ float bf2f(ushort_t u) {
    union { unsigned int i; float f; } x;
    x.i = ((unsigned int)u) << 16;
    return x.f;
}
__device__ __forceinline__ ushort_t f2bf(float f) {
    union { float f; unsigned int i; } x;
    x.f = f;
    unsigned int u = x.i;
    u += 0x7fffu + ((u >> 16) & 1u);   // round-to-nearest-even
    return (ushort_t)(u >> 16);
}

// ---------------- multi-head linked-list segment index ----------------
// 4 interleaved lists per segment: head4[seg*4+k], k = edge_id & 3.
// meta[i] = (src[i], prev edge in same (seg,k) list). One 8B load per hop.

__global__ void init_head(int* __restrict__ head, int n) {
    int i = blockIdx.x * 256 + threadIdx.x;
    if (i < n) head[i] = -1;
}

__global__ void link_kernel(const int* __restrict__ src, const int* __restrict__ dst,
                            const int* __restrict__ et,
                            int* head, int2* __restrict__ meta, int E) {
    int i = blockIdx.x * 256 + threadIdx.x;
    if (i < E) {
        int seg = dst[i] * RNUM + et[i];
        int prev = atomicExch(&head[seg * 4 + (i & 3)], i);
        meta[i] = make_int2(src[i], prev);
    }
}

// ------- weight transpose + bf16 cast: Wt[r][h][f] = bf16(W[r][f][h]), r=8 -> root -------

__global__ __launch_bounds__(256) void transpose_w(const float* __restrict__ rel_w,
                                                   const float* __restrict__ root_w,
                                                   ushort_t* __restrict__ Wt) {
    int r = blockIdx.x;  // 0..8
    const float* src = (r < 8) ? (rel_w + r * 16384) : root_w;
    __shared__ ushort_t t[128 * 130];
    for (int idx = threadIdx.x; idx < 16384; idx += 256)
        t[(idx >> 7) * 130 + (idx & 127)] = f2bf(src[idx]);
    __syncthreads();
    ushort_t* d = Wt + r * 16384;
    for (int idx = threadIdx.x; idx < 16384; idx += 256)
        d[idx] = t[(idx & 127) * 130 + (idx >> 7)];
}

// ---------------- cast x (f32) into compact bf16 buffer; pad rows zeroed ----------------

__global__ void cast_x(const float* __restrict__ x, ushort_t* __restrict__ xc,
                       int total, int totalPad) {
    int i = (blockIdx.x * 256 + threadIdx.x) * 8;
    if (i >= totalPad) return;
    ushort_t o[8];
    if (i < total) {
        float4 v0 = *(const float4*)(x + i);
        float4 v1 = *(const float4*)(x + i + 4);
        o[0] = f2bf(v0.x); o[1] = f2bf(v0.y); o[2] = f2bf(v0.z); o[3] = f2bf(v0.w);
        o[4] = f2bf(v1.x); o[5] = f2bf(v1.y); o[6] = f2bf(v1.z); o[7] = f2bf(v1.w);
    } else {
#pragma unroll
        for (int k = 0; k < 8; ++k) o[k] = 0;
    }
    *(int4v*)(xc + i) = *(int4v*)o;
}

// ---------------- phase A: per-(node,rel) segment means ----------------
// One quarter-wave (16 lanes x 16B) per segment; the segment's 4 sub-chains
// walked interleaved (4 independent gathers in flight). Exec-masked guards:
// dead chains issue no loads. All addresses are pow2 shifts.
// Mean store is NONTEMPORAL: Mm is write-once/read-once-by-GEMM; a cached
// store read-allocates (RFO) the missing line first -- counter evidence:
// FETCH was ~131MB vs ~26MB compulsory, excess == WRITE_SIZE (100MB).

__global__ __launch_bounds__(256) void seg_mean(const int4v* __restrict__ head4,
                                                const int2* __restrict__ meta,
                                                const ushort_t* __restrict__ X,   // [NPAD][128]
                                                ushort_t* __restrict__ Mm,        // [NPAD][8][128]
                                                int NSEG) {
    int t = blockIdx.x * 256 + threadIdx.x;
    int seg = t >> 4;
    int l16 = t & 15;
    if (seg >= NSEG) return;
    const ushort_t* gbase = X + l16 * 8;

    float acc[8];
#pragma unroll
    for (int k = 0; k < 8; ++k) acc[k] = 0.f;

    int4v h4 = head4[seg];           // 4 sub-chain heads in one 16B load
    int j[4], s[4], n[4];
#pragma unroll
    for (int c = 0; c < 4; ++c) j[c] = h4[c];
#pragma unroll
    for (int c = 0; c < 4; ++c)
        if (j[c] >= 0) { int2 m = meta[j[c]]; s[c] = m.x; n[c] = m.y; }

    int cnt = 0;
    // loop while ANY sub-chain active (AND of ids has sign bit set iff all -1)
    while ((j[0] & j[1] & j[2] & j[3]) >= 0) {
        int4v v[4];
#pragma unroll
        for (int c = 0; c < 4; ++c)
            if (j[c] >= 0) v[c] = *(const int4v*)(gbase + ((size_t)s[c] << 7));
        int2 m2[4];
#pragma unroll
        for (int c = 0; c < 4; ++c)
            if (j[c] >= 0 && n[c] >= 0) m2[c] = meta[n[c]];
#pragma unroll
        for (int c = 0; c < 4; ++c) {
            if (j[c] >= 0) {
                const ushort_t* p = (const ushort_t*)&v[c];
#pragma unroll
                for (int k = 0; k < 8; ++k) acc[k] += bf2f(p[k]);
                ++cnt;
                j[c] = n[c];
                s[c] = m2[c].x;
                n[c] = m2[c].y;
            }
        }
    }

    float sc = (cnt > 0) ? 1.0f / (float)cnt : 0.f;
    ushort_t ov[8];
#pragma unroll
    for (int k = 0; k < 8; ++k) ov[k] = f2bf(acc[k] * sc);
    __builtin_nontemporal_store(*(int4v*)ov,
                                (int4v*)(Mm + ((size_t)seg << 7) + l16 * 8));
}

// ---------------- phase B: dense GEMM  C[128n x 128h] = [Mm | Xc] @ Wt^T ----------------
// Register-staged K-slot pipeline: while slot r computes from LDS, slot r+1's
// A/B chunks are already in flight to registers; after the post-compute
// barrier they are ds_written into the XOR-swizzled LDS tiles. Mm rows are
// consumed by exactly one block -> nontemporal loads (no reuse; keeps
// X/h1c/Wt resident in L2/L3 for the gather kernels).

template <bool FINAL>
__global__ __launch_bounds__(256, 2) void rgcn_gemm(
    const ushort_t* __restrict__ Mm,   // [NPAD][8*128]
    const ushort_t* __restrict__ Xc,   // [NPAD][128]  (slot 8 / root input)
    const ushort_t* __restrict__ Wt,   // [9][128][128]
    const float* __restrict__ bias, float* __restrict__ outF,
    ushort_t* __restrict__ Xout, int N) {
    __shared__ ushort_t As[128 * 128];
    __shared__ ushort_t Bs[128 * 128];
    int tid = threadIdx.x;
    int wid = tid >> 6, lane = tid & 63;
    int l16 = lane & 15, q = lane >> 4;
    int nodeBase = blockIdx.x * 128;

    f32x4 acc[2][8];
#pragma unroll
    for (int rt = 0; rt < 2; ++rt)
#pragma unroll
        for (int ct = 0; ct < 8; ++ct) acc[rt][ct] = (f32x4){0.f, 0.f, 0.f, 0.f};

    int4v aReg[8], bReg[8];

    auto issueLoads = [&](int r) {
#pragma unroll
        for (int i = 0; i < 8; ++i) {
            int L = i * 256 + tid;          // 16B slot index, wave-contiguous
            int row = L >> 4;               // 0..127
            int c = (L & 15) ^ (row & 15);  // logical chunk for this slot (swizzle)
            if (r < 8) {
                aReg[i] = __builtin_nontemporal_load(
                    (const int4v*)(Mm + ((size_t)(nodeBase + row) << 10) + r * 128 + c * 8));
            } else {
                aReg[i] = *(const int4v*)(Xc + ((size_t)(nodeBase + row) << 7) + c * 8);
            }
            bReg[i] = *(const int4v*)(Wt + r * 16384 + row * 128 + c * 8);
        }
    };
    auto writeLds = [&]() {
#pragma unroll
        for (int i = 0; i < 8; ++i) {
            int L = i * 256 + tid;
            *(int4v*)((char*)As + (size_t)L * 16) = aReg[i];
            *(int4v*)((char*)Bs + (size_t)L * 16) = bReg[i];
        }
    };

    issueLoads(0);
    writeLds();
    __syncthreads();

    for (int r = 0; r < 9; ++r) {
        if (r < 8) issueLoads(r + 1);       // in flight across the compute phase
#pragma unroll
        for (int s = 0; s < 4; ++s) {
            int pos = ((s * 4 + q) ^ l16) * 16;
            short8 a0 = *(const short8*)((const char*)As + ((2 * wid + 0) * 16 + l16) * 256 + pos);
            short8 a1 = *(const short8*)((const char*)As + ((2 * wid + 1) * 16 + l16) * 256 + pos);
#pragma unroll
            for (int ct = 0; ct < 8; ++ct) {
                short8 b = *(const short8*)((const char*)Bs + (ct * 16 + l16) * 256 + pos);
                acc[0][ct] = __builtin_amdgcn_mfma_f32_16x16x32_bf16(a0, b, acc[0][ct], 0, 0, 0);
                acc[1][ct] = __builtin_amdgcn_mfma_f32_16x16x32_bf16(a1, b, acc[1][ct], 0, 0, 0);
            }
        }
        __syncthreads();                     // all LDS reads of slot r done
        if (r < 8) {
            writeLds();                      // waits vmcnt on the staged regs only
            __syncthreads();                 // writes visible before next compute
        }
    }

    // epilogue: C layout col = lane&15, row = q*4 + reg
#pragma unroll
    for (int rt = 0; rt < 2; ++rt) {
#pragma unroll
        for (int ct = 0; ct < 8; ++ct) {
            int h = ct * 16 + l16;
            float bv = bias[h];
#pragma unroll
            for (int reg = 0; reg < 4; ++reg) {
                int node = nodeBase + (2 * wid + rt) * 16 + q * 4 + reg;
                float v = acc[rt][ct][reg] + bv;
                if (FINAL) {
                    if (node < N)
                        __builtin_nontemporal_store(v, outF + (size_t)node * FDIM + h);
                } else {
                    // pad rows written as 0 (keeps h1c defined; acc there is garbage)
                    // h1c is gathered by the next seg_mean -> CACHED store (L3-resident)
                    Xout[(size_t)node * FDIM + h] =
                        (node < N) ? f2bf(fmaxf(v, 0.f)) : (ushort_t)0;
                }
            }
        }
    }
}

__global__ void copy_emb(const float* __restrict__ e, float* __restrict__ out, int n) {
    int i = blockIdx.x * 256 + threadIdx.x;
    if (i < n) out[i] = e[i];
}

// ---------------- launch ----------------

extern "C" void kernel_launch(void* const* d_in, const int* in_sizes, int n_in,
                              void* d_out, int out_size, void* d_ws, size_t ws_size,
                              hipStream_t stream) {
    const float* x        = (const float*)d_in[0];
    const int* edge_index = (const int*)d_in[1];
    const int* edge_type  = (const int*)d_in[2];
    const float* rel_w0   = (const float*)d_in[3];
    const float* root_w0  = (const float*)d_in[4];
    const float* bias0    = (const float*)d_in[5];
    const float* rel_w1   = (const float*)d_in[6];
    const float* root_w1  = (const float*)d_in[7];
    const float* bias1    = (const float*)d_in[8];
    const float* rel_emb  = (const float*)d_in[9];

    int N = in_sizes[0] / FDIM;   // 50000
    int E = in_sizes[1] / 2;      // 800000
    int NSEG = N * RNUM;          // 400000
    const int* src = edge_index;
    const int* dst = edge_index + E;

    int nb_gemm = (N + 127) / 128;      // 391
    int NPAD = nb_gemm * 128;           // 50048

    char* w = (char*)d_ws;
    auto alloc = [&](size_t bytes) -> char* {
        char* p = w;
        w += (bytes + 255) & ~(size_t)255;
        return p;
    };
    int* head     = (int*)alloc((size_t)NSEG * 4 * 4);          // 4 sub-lists per segment
    int2* meta    = (int2*)alloc((size_t)E * 8);
    ushort_t* Wt  = (ushort_t*)alloc((size_t)2 * 9 * 16384 * 2);
    ushort_t* xc  = (ushort_t*)alloc((size_t)NPAD * FDIM * 2);        // 12.8 MB
    ushort_t* h1c = (ushort_t*)alloc((size_t)NPAD * FDIM * 2);        // 12.8 MB
    ushort_t* Mm  = (ushort_t*)alloc((size_t)NPAD * RNUM * FDIM * 2); // ~102.5 MB
    (void)ws_size; (void)n_in; (void)out_size;

    int nb_head = (NSEG * 4 + 255) / 256;
    int nb_E    = (E + 255) / 256;
    int nb_mean = (NSEG * 16) / 256;                 // 25000
    int nb_cast = (NPAD * FDIM) / (256 * 8);         // 3128

    init_head<<<nb_head, 256, 0, stream>>>(head, NSEG * 4);
    link_kernel<<<nb_E, 256, 0, stream>>>(src, dst, edge_type, head, meta, E);
    transpose_w<<<9, 256, 0, stream>>>(rel_w0, root_w0, Wt);
    transpose_w<<<9, 256, 0, stream>>>(rel_w1, root_w1, Wt + 9 * 16384);
    cast_x<<<nb_cast, 256, 0, stream>>>(x, xc, N * FDIM, NPAD * FDIM);

    seg_mean<<<nb_mean, 256, 0, stream>>>((const int4v*)head, meta, xc, Mm, NSEG);
    rgcn_gemm<false><<<nb_gemm, 256, 0, stream>>>(Mm, xc, Wt, bias0, nullptr, h1c, N);
    seg_mean<<<nb_mean, 256, 0, stream>>>((const int4v*)head, meta, h1c, Mm, NSEG);
    rgcn_gemm<true><<<nb_gemm, 256, 0, stream>>>(Mm, h1c, Wt + 9 * 16384, bias1,
                                                 (float*)d_out, nullptr, N);
    copy_emb<<<4, 256, 0, stream>>>(rel_emb, (float*)d_out + (size_t)N * FDIM,
                                    in_sizes[9]);
}

// Round 7
// 315.228 us; speedup vs baseline: 1.0546x; 1.0546x over previous
//
#include <hip/hip_runtime.h>

typedef unsigned short ushort_t;
typedef __attribute__((ext_vector_type(8))) short short8;
typedef __attribute__((ext_vector_type(4))) float f32x4;
typedef __attribute__((ext_vector_type(4))) int int4v;

#define RNUM 8
#define FDIM 128

__device__ __forceinline__ float bf2f(ushort_t u) {
    union { unsigned int i; float f; } x;
    x.i = ((unsigned int)u) << 16;
    return x.f;
}
__device__ __forceinline__ ushort_t f2bf(float f) {
    union { float f; unsigned int i; } x;
    x.f = f;
    unsigned int u = x.i;
    u += 0x7fffu + ((u >> 16) & 1u);   // round-to-nearest-even
    return (ushort_t)(u >> 16);
}

// ---------------- multi-head linked-list segment index ----------------
// 4 interleaved lists per segment: head4[seg*4+k], k = edge_id & 3.
// meta[i] = (src[i], prev edge in same (seg,k) list). One 8B load per hop.

__global__ void init_head(int* __restrict__ head, int n) {
    int i = blockIdx.x * 256 + threadIdx.x;
    if (i < n) head[i] = -1;
}

__global__ void link_kernel(const int* __restrict__ src, const int* __restrict__ dst,
                            const int* __restrict__ et,
                            int* head, int2* __restrict__ meta, int E) {
    int i = blockIdx.x * 256 + threadIdx.x;
    if (i < E) {
        int seg = dst[i] * RNUM + et[i];
        int prev = atomicExch(&head[seg * 4 + (i & 3)], i);
        meta[i] = make_int2(src[i], prev);
    }
}

// ------- weight transpose + bf16 cast: Wt[l][r][h][f] = bf16(W_l[r][f][h]), r=8 -> root ----
// both layers in one launch (18 blocks)

__global__ __launch_bounds__(256) void transpose_w(const float* __restrict__ rel_w0,
                                                   const float* __restrict__ root_w0,
                                                   const float* __restrict__ rel_w1,
                                                   const float* __restrict__ root_w1,
                                                   ushort_t* __restrict__ Wt) {
    int b = blockIdx.x;            // 0..17
    int layer = (b >= 9) ? 1 : 0;
    int r = b - layer * 9;         // 0..8
    const float* rel  = layer ? rel_w1 : rel_w0;
    const float* root = layer ? root_w1 : root_w0;
    const float* src = (r < 8) ? (rel + r * 16384) : root;
    __shared__ ushort_t t[128 * 130];
    for (int idx = threadIdx.x; idx < 16384; idx += 256)
        t[(idx >> 7) * 130 + (idx & 127)] = f2bf(src[idx]);
    __syncthreads();
    ushort_t* d = Wt + (layer * 9 + r) * 16384;
    for (int idx = threadIdx.x; idx < 16384; idx += 256)
        d[idx] = t[(idx & 127) * 130 + (idx >> 7)];
}

// ---------------- cast x (f32) into compact bf16 buffer; pad rows zeroed ----------------

__global__ void cast_x(const float* __restrict__ x, ushort_t* __restrict__ xc,
                       int total, int totalPad) {
    int i = (blockIdx.x * 256 + threadIdx.x) * 8;
    if (i >= totalPad) return;
    ushort_t o[8];
    if (i < total) {
        float4 v0 = *(const float4*)(x + i);
        float4 v1 = *(const float4*)(x + i + 4);
        o[0] = f2bf(v0.x); o[1] = f2bf(v0.y); o[2] = f2bf(v0.z); o[3] = f2bf(v0.w);
        o[4] = f2bf(v1.x); o[5] = f2bf(v1.y); o[6] = f2bf(v1.z); o[7] = f2bf(v1.w);
    } else {
#pragma unroll
        for (int k = 0; k < 8; ++k) o[k] = 0;
    }
    *(int4v*)(xc + i) = *(int4v*)o;
}

// ---------------- phase A: per-(node,rel) segment means ----------------
// One quarter-wave (16 lanes x 16B) per segment; the segment's 4 sub-chains
// walked interleaved (4 independent gathers in flight). Exec-masked guards:
// dead chains issue no loads. All addresses pow2 shifts. Plain cached
// stores: Mm stays L3-resident for the GEMM that reads it next (NT stores
// in round 6 evicted it to HBM and regressed the GEMM).
// This kernel is at its pattern roofline (~3.8-4.1 TB/s fabric for random
// 256B gathers, measured stable across rounds 0/3/5) -- do not touch.

__global__ __launch_bounds__(256) void seg_mean(const int4v* __restrict__ head4,
                                                const int2* __restrict__ meta,
                                                const ushort_t* __restrict__ X,   // [NPAD][128]
                                                ushort_t* __restrict__ Mm,        // [NPAD][8][128]
                                                int NSEG) {
    int t = blockIdx.x * 256 + threadIdx.x;
    int seg = t >> 4;
    int l16 = t & 15;
    if (seg >= NSEG) return;
    const ushort_t* gbase = X + l16 * 8;

    float acc[8];
#pragma unroll
    for (int k = 0; k < 8; ++k) acc[k] = 0.f;

    int4v h4 = head4[seg];           // 4 sub-chain heads in one 16B load
    int j[4], s[4], n[4];
#pragma unroll
    for (int c = 0; c < 4; ++c) j[c] = h4[c];
#pragma unroll
    for (int c = 0; c < 4; ++c)
        if (j[c] >= 0) { int2 m = meta[j[c]]; s[c] = m.x; n[c] = m.y; }

    int cnt = 0;
    // loop while ANY sub-chain active (AND of ids has sign bit set iff all -1)
    while ((j[0] & j[1] & j[2] & j[3]) >= 0) {
        int4v v[4];
#pragma unroll
        for (int c = 0; c < 4; ++c)
            if (j[c] >= 0) v[c] = *(const int4v*)(gbase + ((size_t)s[c] << 7));
        int2 m2[4];
#pragma unroll
        for (int c = 0; c < 4; ++c)
            if (j[c] >= 0 && n[c] >= 0) m2[c] = meta[n[c]];
#pragma unroll
        for (int c = 0; c < 4; ++c) {
            if (j[c] >= 0) {
                const ushort_t* p = (const ushort_t*)&v[c];
#pragma unroll
                for (int k = 0; k < 8; ++k) acc[k] += bf2f(p[k]);
                ++cnt;
                j[c] = n[c];
                s[c] = m2[c].x;
                n[c] = m2[c].y;
            }
        }
    }

    float sc = (cnt > 0) ? 1.0f / (float)cnt : 0.f;
    ushort_t ov[8];
#pragma unroll
    for (int k = 0; k < 8; ++k) ov[k] = f2bf(acc[k] * sc);
    *(int4v*)(Mm + ((size_t)seg << 7) + l16 * 8) = *(int4v*)ov;
}

// ---------------- phase B: dense GEMM  C[128n x 128h] = [Mm | Xc] @ Wt^T ----------------
// Register-staged K-slot pipeline (slot r+1's chunks in flight during slot
// r's MFMAs; ds_write after the post-compute barrier). 512 threads / 8 waves
// per block: same tile and LDS as the 256-thread version, but 2.7x the
// wave-level parallelism (16 waves/CU at 2 blocks/CU) so one wave's staging
// vmcnt stall is covered by other waves' MFMAs. Round-6 analysis: at 256
// threads the GEMM ran ~6 waves/CU and the ~900cy staging latency had only
// ~350cy of compute cover -> latency-exposed.

template <bool FINAL>
__global__ __launch_bounds__(512, 4) void rgcn_gemm(
    const ushort_t* __restrict__ Mm,   // [NPAD][8*128]
    const ushort_t* __restrict__ Xc,   // [NPAD][128]  (slot 8 / root input)
    const ushort_t* __restrict__ Wt,   // [9][128][128]
    const float* __restrict__ bias, float* __restrict__ outF,
    ushort_t* __restrict__ Xout, int N) {
    __shared__ ushort_t As[128 * 128];
    __shared__ ushort_t Bs[128 * 128];
    int tid = threadIdx.x;
    int wv = tid >> 6, lane = tid & 63;
    int l16 = lane & 15, q = lane >> 4;
    int nodeBase = blockIdx.x * 128;

    f32x4 acc[8];
#pragma unroll
    for (int ct = 0; ct < 8; ++ct) acc[ct] = (f32x4){0.f, 0.f, 0.f, 0.f};

    int4v aReg[4], bReg[4];

    auto issueLoads = [&](int r) {
#pragma unroll
        for (int i = 0; i < 4; ++i) {
            int L = i * 512 + tid;          // 16B slot index, wave-contiguous
            int row = L >> 4;               // 0..127
            int c = (L & 15) ^ (row & 15);  // logical chunk for this slot (swizzle)
            const ushort_t* ga = (r < 8)
                ? Mm + ((size_t)(nodeBase + row) << 10) + r * 128 + c * 8
                : Xc + ((size_t)(nodeBase + row) << 7) + c * 8;
            aReg[i] = *(const int4v*)ga;
            bReg[i] = *(const int4v*)(Wt + r * 16384 + row * 128 + c * 8);
        }
    };
    auto writeLds = [&]() {
#pragma unroll
        for (int i = 0; i < 4; ++i) {
            int L = i * 512 + tid;
            *(int4v*)((char*)As + (size_t)L * 16) = aReg[i];
            *(int4v*)((char*)Bs + (size_t)L * 16) = bReg[i];
        }
    };

    issueLoads(0);
    writeLds();
    __syncthreads();

    for (int r = 0; r < 9; ++r) {
        if (r < 8) issueLoads(r + 1);       // in flight across the compute phase
#pragma unroll
        for (int s = 0; s < 4; ++s) {
            int pos = ((s * 4 + q) ^ l16) * 16;
            short8 a = *(const short8*)((const char*)As + (wv * 16 + l16) * 256 + pos);
#pragma unroll
            for (int ct = 0; ct < 8; ++ct) {
                short8 b = *(const short8*)((const char*)Bs + (ct * 16 + l16) * 256 + pos);
                acc[ct] = __builtin_amdgcn_mfma_f32_16x16x32_bf16(a, b, acc[ct], 0, 0, 0);
            }
        }
        __syncthreads();                     // all LDS reads of slot r done
        if (r < 8) {
            writeLds();                      // waits vmcnt on the staged regs only
            __syncthreads();                 // writes visible before next compute
        }
    }

    // epilogue: C layout col = lane&15, row = q*4 + reg (within wave's 16-row tile)
#pragma unroll
    for (int ct = 0; ct < 8; ++ct) {
        int h = ct * 16 + l16;
        float bv = bias[h];
#pragma unroll
        for (int reg = 0; reg < 4; ++reg) {
            int node = nodeBase + wv * 16 + q * 4 + reg;
            float v = acc[ct][reg] + bv;
            if (FINAL) {
                if (node < N) outF[(size_t)node * FDIM + h] = v;
            } else {
                // pad rows written as 0 (keeps h1c defined; acc there is garbage)
                Xout[(size_t)node * FDIM + h] =
                    (node < N) ? f2bf(fmaxf(v, 0.f)) : (ushort_t)0;
            }
        }
    }
}

__global__ void copy_emb(const float* __restrict__ e, float* __restrict__ out, int n) {
    int i = blockIdx.x * 256 + threadIdx.x;
    if (i < n) out[i] = e[i];
}

// ---------------- launch ----------------

extern "C" void kernel_launch(void* const* d_in, const int* in_sizes, int n_in,
                              void* d_out, int out_size, void* d_ws, size_t ws_size,
                              hipStream_t stream) {
    const float* x        = (const float*)d_in[0];
    const int* edge_index = (const int*)d_in[1];
    const int* edge_type  = (const int*)d_in[2];
    const float* rel_w0   = (const float*)d_in[3];
    const float* root_w0  = (const float*)d_in[4];
    const float* bias0    = (const float*)d_in[5];
    const float* rel_w1   = (const float*)d_in[6];
    const float* root_w1  = (const float*)d_in[7];
    const float* bias1    = (const float*)d_in[8];
    const float* rel_emb  = (const float*)d_in[9];

    int N = in_sizes[0] / FDIM;   // 50000
    int E = in_sizes[1] / 2;      // 800000
    int NSEG = N * RNUM;          // 400000
    const int* src = edge_index;
    const int* dst = edge_index + E;

    int nb_gemm = (N + 127) / 128;      // 391
    int NPAD = nb_gemm * 128;           // 50048

    char* w = (char*)d_ws;
    auto alloc = [&](size_t bytes) -> char* {
        char* p = w;
        w += (bytes + 255) & ~(size_t)255;
        return p;
    };
    int* head     = (int*)alloc((size_t)NSEG * 4 * 4);          // 4 sub-lists per segment
    int2* meta    = (int2*)alloc((size_t)E * 8);
    ushort_t* Wt  = (ushort_t*)alloc((size_t)2 * 9 * 16384 * 2);
    ushort_t* xc  = (ushort_t*)alloc((size_t)NPAD * FDIM * 2);        // 12.8 MB
    ushort_t* h1c = (ushort_t*)alloc((size_t)NPAD * FDIM * 2);        // 12.8 MB
    ushort_t* Mm  = (ushort_t*)alloc((size_t)NPAD * RNUM * FDIM * 2); // ~102.5 MB
    (void)ws_size; (void)n_in; (void)out_size;

    int nb_head = (NSEG * 4 + 255) / 256;
    int nb_E    = (E + 255) / 256;
    int nb_mean = (NSEG * 16) / 256;                 // 25000
    int nb_cast = (NPAD * FDIM) / (256 * 8);         // 3128

    init_head<<<nb_head, 256, 0, stream>>>(head, NSEG * 4);
    link_kernel<<<nb_E, 256, 0, stream>>>(src, dst, edge_type, head, meta, E);
    transpose_w<<<18, 256, 0, stream>>>(rel_w0, root_w0, rel_w1, root_w1, Wt);
    cast_x<<<nb_cast, 256, 0, stream>>>(x, xc, N * FDIM, NPAD * FDIM);

    seg_mean<<<nb_mean, 256, 0, stream>>>((const int4v*)head, meta, xc, Mm, NSEG);
    rgcn_gemm<false><<<nb_gemm, 512, 0, stream>>>(Mm, xc, Wt, bias0, nullptr, h1c, N);
    seg_mean<<<nb_mean, 256, 0, stream>>>((const int4v*)head, meta, h1c, Mm, NSEG);
    rgcn_gemm<true><<<nb_gemm, 512, 0, stream>>>(Mm, h1c, Wt + 9 * 16384, bias1,
                                                 (float*)d_out, nullptr, N);
    copy_emb<<<4, 256, 0, stream>>>(rel_emb, (float*)d_out + (size_t)N * FDIM,
                                    in_sizes[9]);
}